// Round 7
// baseline (318.069 us; speedup 1.0000x reference)
//
#include <hip/hip_runtime.h>
#include <hip/hip_bf16.h>

typedef __attribute__((ext_vector_type(4))) float f32x4;
typedef __attribute__((ext_vector_type(8))) short s16x8;

#define NCLS 16
#define NCAT 4096
#define NOUT 512
#define NBS  4096

#define BM 128
#define BN 128
#define BK 32                    // k per LDS tile (bf16 elems)
#define NSPLIT 8
#define KSPLIT (NCAT / NSPLIT)   // 512
#define NIT    (KSPLIT / BK)     // 16
#define MAXTILES 48
#define ABYTES 16384             // A plane: 128 rows x (64B hi | 64B lo)
#define BUFSZ  32768             // A + B

// d_ws int layout
#define WS_NT    0
#define WS_CBASE 1     // [17]
#define WS_TCLS  32    // [MAXTILES]
#define WS_TM0   96    // [MAXTILES]
#define WS_SIDX  160   // [4096]

// ---------------- prep: histogram + parallel scan + tile map + scatter ----------------
__global__ __launch_bounds__(256) void prep_kernel(const int* __restrict__ cls,
                                                   int* __restrict__ ws) {
  __shared__ int lcnt[NCLS * 256];
  __shared__ int cb[NCLS];
  const int t = threadIdx.x;

  int cl[16];
  #pragma unroll
  for (int j = 0; j < 16; ++j) cl[j] = cls[j * 256 + t];

  int cnt[NCLS];
  #pragma unroll
  for (int c = 0; c < NCLS; ++c) cnt[c] = 0;
  #pragma unroll
  for (int j = 0; j < 16; ++j) {
    #pragma unroll
    for (int c = 0; c < NCLS; ++c) cnt[c] += (cl[j] == c) ? 1 : 0;
  }
  #pragma unroll
  for (int c = 0; c < NCLS; ++c) lcnt[c * 256 + t] = cnt[c];
  __syncthreads();

  for (int d = 1; d < 256; d <<= 1) {
    int add[NCLS];
    #pragma unroll
    for (int c = 0; c < NCLS; ++c) add[c] = (t >= d) ? lcnt[c * 256 + t - d] : 0;
    __syncthreads();
    #pragma unroll
    for (int c = 0; c < NCLS; ++c) if (t >= d) lcnt[c * 256 + t] += add[c];
    __syncthreads();
  }

  if (t == 0) {
    int acc = 0, ntt = 0;
    for (int c = 0; c < NCLS; ++c) {
      cb[c] = acc;
      ws[WS_CBASE + c] = acc;
      int tot = lcnt[c * 256 + 255];
      for (int m0 = 0; m0 < tot; m0 += BM) {
        ws[WS_TCLS + ntt] = c;
        ws[WS_TM0 + ntt] = m0;
        ++ntt;
      }
      acc += tot;
    }
    ws[WS_CBASE + NCLS] = acc;
    ws[WS_NT] = ntt;
  }
  __syncthreads();

  #pragma unroll
  for (int j = 0; j < 16; ++j) {
    int c = cl[j];
    int within = 0;
    #pragma unroll
    for (int j2 = 0; j2 < 16; ++j2) within += (j2 < j && cl[j2] == c) ? 1 : 0;
    ws[WS_SIDX + cb[c] + (lcnt[c * 256 + t] - cnt[c]) + within] = j * 256 + t;
  }
}

// Split pair into hi/lo bf16 (hi = rn(x), lo = rn(x - hi)); packed u32 each.
__device__ __forceinline__ void pk2(float x0, float x1, unsigned& hb, unsigned& lb) {
  __hip_bfloat162 h2 = __float22bfloat162_rn(make_float2(x0, x1));
  float2 hf = __bfloat1622float2(h2);
  __hip_bfloat162 l2 = __float22bfloat162_rn(make_float2(x0 - hf.x, x1 - hf.y));
  __builtin_memcpy(&hb, &h2, 4);
  __builtin_memcpy(&lb, &l2, 4);
}

// 16 f32 (4x f32x4) -> hi 2x uint4, lo 2x uint4 (k-ascending bf16 order)
__device__ __forceinline__ void cvt16(const f32x4* r, uint4* H, uint4* L) {
  #pragma unroll
  for (int j = 0; j < 4; ++j) {
    unsigned h0, l0, h1, l1;
    pk2(r[j][0], r[j][1], h0, l0);
    pk2(r[j][2], r[j][3], h1, l1);
    ((unsigned*)H)[2 * j]     = h0;
    ((unsigned*)H)[2 * j + 1] = h1;
    ((unsigned*)L)[2 * j]     = l0;
    ((unsigned*)L)[2 * j + 1] = l1;
  }
}

// ------- grouped GEMM: reg-staged convert-at-stage, bf16 LDS, 1 barrier/iter -------
__global__ __launch_bounds__(256, 2) void gemm_kernel(const float* __restrict__ batch,
                                                      const float* __restrict__ W,
                                                      const int* __restrict__ ws,
                                                      float* __restrict__ out) {
  const int tile = blockIdx.x;
  if (tile >= ws[WS_NT]) return;
  const int c    = ws[WS_TCLS + tile];
  const int m0   = ws[WS_TM0 + tile];
  const int base = ws[WS_CBASE + c];
  const int Mc   = ws[WS_CBASE + c + 1] - base;
  const int n0   = blockIdx.y * BN;
  const int k0   = blockIdx.z * KSPLIT;
  const int* sidx = ws + WS_SIDX + base;

  __shared__ char lds[2 * BUFSZ];  // 64 KiB: 2 x [A 16K | B 16K], bf16 hi|lo rows

  const int t    = threadIdx.x;
  const int lane = t & 63;
  const int wv   = t >> 6;
  const int l15  = lane & 15;

  // staging map: thread t -> row r, k-half h (16 f32 = 64 B contiguous)
  const int r = t >> 1;
  const int h = t & 1;
  const int swzw = (r & 7) << 4;
  const int ar = sidx[min(m0 + r, Mc - 1)];
  const char* abase = (const char*)(batch + (size_t)ar * NCAT + k0) + h * 64;
  const char* bbase = (const char*)(W + ((size_t)c * NOUT + n0 + r) * NCAT + k0) + h * 64;

  const int wm   = (wv >> 1) * 64;
  const int wn   = (wv & 1) * 64;
  const int kg16 = (lane >> 4) * 16;   // byte offset of lane's 8-bf16 k-group
  const int srd  = (l15 & 7) << 4;     // read-side XOR (row&7 == l15&7)

  f32x4 ra[4], rb[4];

  #define LOADR(IT)                                                \
    do {                                                           \
      const char* ap_ = abase + (IT) * 128;                        \
      const char* bp_ = bbase + (IT) * 128;                        \
      _Pragma("unroll")                                            \
      for (int j_ = 0; j_ < 4; ++j_) {                             \
        ra[j_] = *(const f32x4*)(ap_ + j_ * 16);                   \
        rb[j_] = *(const f32x4*)(bp_ + j_ * 16);                   \
      }                                                            \
    } while (0)

  // convert regs and write to buffer `bo` (byte offset of buffer)
  #define CVTWRITE(bo)                                                          \
    do {                                                                        \
      uint4 H_[2], L_[2];                                                       \
      cvt16(ra, H_, L_);                                                        \
      char* d_ = lds + (bo) + r * 128;                                          \
      *(uint4*)(d_ + ((h * 32) ^ swzw))        = H_[0];                         \
      *(uint4*)(d_ + ((h * 32 + 16) ^ swzw))   = H_[1];                         \
      *(uint4*)(d_ + ((64 + h * 32) ^ swzw))      = L_[0];                      \
      *(uint4*)(d_ + ((64 + h * 32 + 16) ^ swzw)) = L_[1];                      \
      cvt16(rb, H_, L_);                                                        \
      char* e_ = lds + (bo) + ABYTES + r * 128;                                 \
      *(uint4*)(e_ + ((h * 32) ^ swzw))        = H_[0];                         \
      *(uint4*)(e_ + ((h * 32 + 16) ^ swzw))   = H_[1];                         \
      *(uint4*)(e_ + ((64 + h * 32) ^ swzw))      = L_[0];                      \
      *(uint4*)(e_ + ((64 + h * 32 + 16) ^ swzw)) = L_[1];                      \
    } while (0)

  f32x4 acc[4][4];
  #pragma unroll
  for (int i = 0; i < 4; ++i)
    #pragma unroll
    for (int j = 0; j < 4; ++j) acc[i][j] = (f32x4){0.f, 0.f, 0.f, 0.f};

  // prologue: tile0 -> buf0; issue tile1 loads; barrier
  LOADR(0);
  CVTWRITE(0);
  LOADR(1);
  asm volatile("s_waitcnt lgkmcnt(0)" ::: "memory");
  __builtin_amdgcn_s_barrier();
  asm volatile("" ::: "memory");

  for (int it = 0; it < NIT; ++it) {
    const int cur = it & 1;
    // stage: convert tile it+1 (regs) into the other buffer, then refill regs
    if (it + 1 < NIT) CVTWRITE((cur ^ 1) * BUFSZ);
    if (it + 2 < NIT) LOADR(it + 2);

    // compute on buf[cur]: ds_read_b128 -> fragments -> MFMA
    const char* const bufA = lds + cur * BUFSZ;
    const char* const bufB = bufA + ABYTES;
    s16x8 Ah[4], Al[4], Bh[4], Bl[4];
    #pragma unroll
    for (int i = 0; i < 4; ++i) {
      const char* rp = bufA + (wm + i * 16 + l15) * 128;
      Ah[i] = *(const s16x8*)(rp + (kg16 ^ srd));
      Al[i] = *(const s16x8*)(rp + ((64 + kg16) ^ srd));
      const char* rq = bufB + (wn + i * 16 + l15) * 128;
      Bh[i] = *(const s16x8*)(rq + (kg16 ^ srd));
      Bl[i] = *(const s16x8*)(rq + ((64 + kg16) ^ srd));
    }
    __builtin_amdgcn_s_setprio(1);
    #pragma unroll
    for (int i = 0; i < 4; ++i)
      #pragma unroll
      for (int j = 0; j < 4; ++j) {
        acc[i][j] = __builtin_amdgcn_mfma_f32_16x16x32_bf16(Ah[i], Bh[j], acc[i][j], 0, 0, 0);
        acc[i][j] = __builtin_amdgcn_mfma_f32_16x16x32_bf16(Ah[i], Bl[j], acc[i][j], 0, 0, 0);
        acc[i][j] = __builtin_amdgcn_mfma_f32_16x16x32_bf16(Al[i], Bh[j], acc[i][j], 0, 0, 0);
      }
    __builtin_amdgcn_s_setprio(0);

    // iter boundary: LDS ops done, barrier (do NOT drain vmcnt — loads stay in flight)
    asm volatile("s_waitcnt lgkmcnt(0)" ::: "memory");
    __builtin_amdgcn_s_barrier();
    asm volatile("" ::: "memory");
  }
  #undef LOADR
  #undef CVTWRITE

  // ---- epilogue: C/D layout col=lane&15, row=(lane>>4)*4+reg ----
  const int r4 = (lane >> 4) * 4;
  #pragma unroll
  for (int i = 0; i < 4; ++i) {
    #pragma unroll
    for (int jj = 0; jj < 4; ++jj) {
      const int mloc = wm + i * 16 + r4 + jj;
      const int gm = m0 + mloc;
      if (gm < Mc) {
        const int sample = sidx[gm];
        float* orow = out + (size_t)sample * NOUT + n0 + wn;
        #pragma unroll
        for (int j = 0; j < 4; ++j) {
          atomicAdd(orow + j * 16 + l15, acc[i][j][jj]);
        }
      }
    }
  }
}

extern "C" void kernel_launch(void* const* d_in, const int* in_sizes, int n_in,
                              void* d_out, int out_size, void* d_ws, size_t ws_size,
                              hipStream_t stream) {
  const float* batch = (const float*)d_in[0];
  const int*   cls   = (const int*)d_in[1];
  const float* W     = (const float*)d_in[2];
  float* out = (float*)d_out;
  int*   ws  = (int*)d_ws;

  prep_kernel<<<1, 256, 0, stream>>>(cls, ws);
  hipMemsetAsync(d_out, 0, (size_t)out_size * sizeof(float), stream);
  gemm_kernel<<<dim3(MAXTILES, NOUT / BN, NSPLIT), 256, 0, stream>>>(batch, W, ws, out);
}